// Round 9
// baseline (121.443 us; speedup 1.0000x reference)
//
#include <hip/hip_runtime.h>

typedef float v2f __attribute__((ext_vector_type(2)));

#define NB 32
#define N0 20000
#define N1 10000
#define N2 10000
#define NF4_A 10000        // float4s per (b, side) beta_0 stream
#define NF4_E0 5000        // float4s of ext0 per b
#define NF4_E 10000        // float4s of ext0+ext1 per b
#define NCH 157            // ceil(10000/64): 64-float4 chunks per A stream
#define T_A 4              // A-role chunk stride (4 tchunk blocks/stream)
#define KC_A 8             // centers per A wave
#define KC_B 16            // centers per E block
#define NBINS 4096
#define NBLK 512           // total blocks
#define SENT 3.0e4f        // sentinel: per-term contribution ~ -1e-10

// R9: R8's fixes (residency, E prefetch) changed nothing -> wall is not
// occupancy/latency of roles; testing block-granularity/ramp: same total
// work in 512 blocks x 512 threads (4x fatter, ~4x fewer). A-blocks:
// 8 waves share one chunk stream (8x L1 reuse), each wave owns 8 of the
// 64 centers (no 'half' split). E-blocks: R7 hist path at 512 threads.
// Also folds tpl into the LAST-finishing block (counter at out[4096],
// release/acquire threadfence), deleting the tpl dispatch + gap.
// All inner loops byte-identical to R7/R8-validated code.
__global__ __launch_bounds__(512, 4) void hat_kernel(
    const float* __restrict__ up0, const float* __restrict__ down0,
    const float* __restrict__ ext0, const float* __restrict__ ext1,
    const float* __restrict__ centers, const float* __restrict__ radius,
    float* __restrict__ out)
{
    const int tid  = threadIdx.x;
    const int lane = tid & 63;
    const int wave = tid >> 6;
    const float r  = fabsf(radius[0]);
    const int slot = blockIdx.x;

    __shared__ unsigned hist[NBINS];     // 16 KB (E-role)
    __shared__ float    red[8 * KC_B];   // E reduction / tpl scratch
    __shared__ unsigned lastFlag;

    if (slot < 256) {
        // ============ E-role: ext points, 1-D binned (R7-validated) ========
        const int id   = slot;
        const int cc   = id & 3;         // 4 chunks of 16 centers
        const int side = (id >> 2) & 1;  // 0 = up (use y), 1 = down (use x)
        const int b    = id >> 3;
        const int cbase = cc * KC_B;

        for (int j = tid; j < NBINS; j += 512) hist[j] = 0;
        __syncthreads();

        // Build: one pass over ext0|ext1 as float4 (2 points each),
        // unconditional clamped pointer-select load, prefetched 1 ahead.
        const float4* e0 = (const float4*)(ext0 + (size_t)b * (N1*2));
        const float4* e1 = (const float4*)(ext1 + (size_t)b * (N2*2));
        #define EPTR(I) ((I) < NF4_E0 ? (e0 + (I)) : (e1 + ((I) - NF4_E0)))
        float4 q = *EPTR(tid);
        for (int i = tid; i < NF4_E; i += 512) {
            const float4 qc = q;
            q = *EPTR(min(i + 512, NF4_E - 1));
            const float vv0 = (side == 0) ? qc.y : qc.x;
            const float vv1 = (side == 0) ? qc.w : qc.z;
            int b0 = (int)(vv0 * (float)NBINS);
            int b1 = (int)(vv1 * (float)NBINS);
            b0 = min(max(b0, 0), NBINS - 1);
            b1 = min(max(b1, 0), NBINS - 1);
            atomicAdd(&hist[b0], 1u);
            atomicAdd(&hist[b1], 1u);
        }
        #undef EPTR
        __syncthreads();

        // centers: n_k(vv) = max(|1-(cx+cy)|, 2|vv - (1+cx-cy)/2|)
        float Ak[KC_B], mk[KC_B];
        #pragma unroll
        for (int k = 0; k < KC_B; ++k) {
            const float cx = centers[2*(cbase+k)];
            const float cy = centers[2*(cbase+k)+1];
            Ak[k] = fabsf(1.0f - (cx + cy));
            mk[k] = 0.5f * (1.0f + (cx - cy));
        }

        float part[KC_B];
        #pragma unroll
        for (int k = 0; k < KC_B; ++k) part[k] = 0.f;

        #pragma unroll
        for (int jj = 0; jj < NBINS/512; ++jj) {
            const int j = jj*512 + tid;
            const float cntf = (float)hist[j];
            const float vvj  = ((float)j + 0.5f) * (1.0f/(float)NBINS);
            #pragma unroll
            for (int k = 0; k < KC_B; ++k) {
                const float s  = vvj - mk[k];
                const float tt = fmaxf(Ak[k], 2.0f*fabsf(s));
                const float d1 = 1.0f + tt;
                const float rn = r - tt;
                const float d2 = 1.0f + fabsf(rn);
                const float rc = __builtin_amdgcn_rcpf(d1 * d2);
                part[k] = fmaf(cntf * (d2 - d1), rc, part[k]);
            }
        }

        // KC=16 butterfly (validated): center (lane>>2)&15 in part[0]
        {
            #pragma unroll
            for (int k = 0; k < 8; ++k) {
                const bool hi = lane & 32;
                const float send = hi ? part[k]   : part[k+8];
                const float keep = hi ? part[k+8] : part[k];
                part[k] = keep + __shfl_xor(send, 32, 64);
            }
            #pragma unroll
            for (int k = 0; k < 4; ++k) {
                const bool hi = lane & 16;
                const float send = hi ? part[k]   : part[k+4];
                const float keep = hi ? part[k+4] : part[k];
                part[k] = keep + __shfl_xor(send, 16, 64);
            }
            #pragma unroll
            for (int k = 0; k < 2; ++k) {
                const bool hi = lane & 8;
                const float send = hi ? part[k]   : part[k+2];
                const float keep = hi ? part[k+2] : part[k];
                part[k] = keep + __shfl_xor(send, 8, 64);
            }
            {
                const bool hi = lane & 4;
                const float send = hi ? part[0] : part[1];
                const float keep = hi ? part[1] : part[0];
                part[0] = keep + __shfl_xor(send, 4, 64);
            }
            part[0] += __shfl_xor(part[0], 2, 64);
            part[0] += __shfl_xor(part[0], 1, 64);
        }
        if ((lane & 3) == 0) red[wave * KC_B + (lane >> 2)] = part[0];
        __syncthreads();
        if (tid < KC_B) {
            float s = 0.f;
            #pragma unroll
            for (int w2 = 0; w2 < 8; ++w2) s += red[w2 * KC_B + tid];
            atomicAdd(&out[b*128 + side*64 + cbase + tid], s);
        }
    } else {
        // ========= A-role: beta_0 points, exact 2-D (R6-validated) =========
        // aid = (b<<3) | (side<<2) | tchunk; wave owns centers [wave*8, +8)
        const int aid    = slot - 256;
        const int tchunk = aid & 3;
        const int side   = (aid >> 2) & 1;
        const int b      = aid >> 3;
        const int cbase  = wave * KC_A;
        const int outBase = b*128 + side*64 + cbase;

        v2f nuc[KC_A], nvc[KC_A];
        #pragma unroll
        for (int k = 0; k < KC_A; ++k) {
            const float cx = centers[2*(cbase+k)];
            const float cy = centers[2*(cbase+k)+1];
            nuc[k] = (v2f){-(cx + cy), -(cx + cy)};
            nvc[k] = (v2f){-(cx - cy), -(cx - cy)};
        }

        const float4* base0 = (const float4*)((side == 0 ? up0 : down0) + (size_t)b * (N0*2));

        v2f acc[KC_A];
        #pragma unroll
        for (int k = 0; k < KC_A; ++k) acc[k] = (v2f){0.f, 0.f};
        const v2f one2 = (v2f){1.f, 1.f};

        // All 8 waves walk the SAME chunk stream (L1 reuse), each owning
        // its 8-center group. Unconditional clamped load, prefetched.
        float4 q = base0[min(tchunk*64 + lane, NF4_A - 1)];
        for (int t = tchunk; t < NCH; t += T_A) {
            const float4 qc = q;
            const int tn = t + T_A;
            if (tn < NCH) {                       // wave-uniform
                q = base0[min(tn*64 + lane, NF4_A - 1)];
            }

            v2f u_ = (v2f){qc.x + qc.y, qc.z + qc.w};
            v2f v_ = (v2f){qc.x - qc.y, qc.z - qc.w};
            if (t*64 + 63 >= NF4_A) {             // wave-uniform: only t==156
                const bool bad = (t*64 + lane) >= NF4_A;
                u_.x = bad ? SENT : u_.x;  u_.y = bad ? SENT : u_.y;
                v_.x = bad ? 0.f  : v_.x;  v_.y = bad ? 0.f  : v_.y;
            }

            #pragma unroll
            for (int k = 0; k < KC_A; ++k) {
                const v2f du = u_ + nuc[k];
                const v2f dv = v_ + nvc[k];
                const float tt0 = fmaxf(fabsf(du.x), fabsf(dv.x));
                const float tt1 = fmaxf(fabsf(du.y), fabsf(dv.y));
                const v2f tt = (v2f){tt0, tt1};
                const v2f d1 = tt + one2;
                const float rn0 = r - tt0;
                const float rn1 = r - tt1;
                const v2f d2 = (v2f){1.f + fabsf(rn0), 1.f + fabsf(rn1)};
                const v2f dd  = d1 * d2;
                const v2f num = d2 - d1;
                const v2f rc  = (v2f){__builtin_amdgcn_rcpf(dd.x),
                                      __builtin_amdgcn_rcpf(dd.y)};
                acc[k] = __builtin_elementwise_fma(num, rc, acc[k]);
            }
        }

        float a1[KC_A];
        #pragma unroll
        for (int k = 0; k < KC_A; ++k) a1[k] = acc[k].x + acc[k].y;

        // KC=8 butterfly (validated): value (lane>>3)&7 at (lane&7)==0
        {
            #pragma unroll
            for (int k = 0; k < 4; ++k) {
                const bool hi = lane & 32;
                const float send = hi ? a1[k]   : a1[k+4];
                const float keep = hi ? a1[k+4] : a1[k];
                a1[k] = keep + __shfl_xor(send, 32, 64);
            }
            #pragma unroll
            for (int k = 0; k < 2; ++k) {
                const bool hi = lane & 16;
                const float send = hi ? a1[k]   : a1[k+2];
                const float keep = hi ? a1[k+2] : a1[k];
                a1[k] = keep + __shfl_xor(send, 16, 64);
            }
            {
                const bool hi = lane & 8;
                const float send = hi ? a1[0] : a1[1];
                const float keep = hi ? a1[1] : a1[0];
                a1[0] = keep + __shfl_xor(send, 8, 64);
            }
            a1[0] += __shfl_xor(a1[0], 4, 64);
            a1[0] += __shfl_xor(a1[0], 2, 64);
            a1[0] += __shfl_xor(a1[0], 1, 64);
        }
        if ((lane & 7) == 0) {
            atomicAdd(&out[outBase + (lane >> 3)], a1[0]);
        }
    }

    // ===== epilogue: last-finishing block computes tpl in-kernel =====
    // out[4096] doubles as the block counter (zeroed by memset; only the
    // last block overwrites it with the final tpl value).
    __syncthreads();                 // block's atomics drained before count
    if (tid == 0) {
        __threadfence();             // release: make our adds visible
        const unsigned old = atomicAdd((unsigned*)&out[NB*128], 1u);
        lastFlag = (old == NBLK - 1) ? 1u : 0u;
    }
    __syncthreads();
    if (lastFlag) {
        __threadfence();             // acquire: invalidate L1, see all adds
        float s = 0.f;
        for (int i = tid; i < NB*64; i += 512) {
            const int b2 = i >> 6, k = i & 63;
            const float d = out[b2*128 + k] - out[b2*128 + 64 + k];
            s = fmaf(d, d, s);
        }
        #pragma unroll
        for (int o = 32; o > 0; o >>= 1) s += __shfl_xor(s, o, 64);
        if (lane == 0) red[wave] = s;
        __syncthreads();
        if (tid == 0) {
            float t2 = 0.f;
            #pragma unroll
            for (int w2 = 0; w2 < 8; ++w2) t2 += red[w2];
            out[NB*128] = -t2;
        }
    }
}

extern "C" void kernel_launch(void* const* d_in, const int* in_sizes, int n_in,
                              void* d_out, int out_size, void* d_ws, size_t ws_size,
                              hipStream_t stream) {
    const float* up0     = (const float*)d_in[0];
    const float* down0   = (const float*)d_in[1];
    const float* ext0    = (const float*)d_in[2];
    const float* ext1    = (const float*)d_in[3];
    const float* centers = (const float*)d_in[4];
    const float* radius  = (const float*)d_in[5];
    float* out = (float*)d_out;

    // zero accumulators AND the counter/tpl slot at out[4096]
    // (harness poisons d_out with 0xAA each iteration)
    hipMemsetAsync(out, 0, (NB * 128 + 1) * sizeof(float), stream);

    hat_kernel<<<dim3(NBLK), dim3(512), 0, stream>>>(
        up0, down0, ext0, ext1, centers, radius, out);
}